// Round 1
// baseline (344.276 us; speedup 1.0000x reference)
//
#include <hip/hip_runtime.h>

typedef unsigned int u32;

#define NIMG 16
#define HH 512
#define WW 512
#define HWSZ (HH*WW)
#define TOPN 2621u
#define TIE_CAP 8192
#define GR 40

// ---------------- channel min + guidance ----------------
__global__ void k_chanmin_guid(const float* __restrict__ x,
                               float* __restrict__ m, float* __restrict__ g){
  int i = blockIdx.x*256 + threadIdx.x;
  int n = i >> 18;
  int hw = i & (HWSZ-1);
  const float* p = x + (size_t)n*3*HWSZ + hw;
  float x0 = p[0], x1 = p[HWSZ], x2 = p[2*HWSZ];
  float i0 = (x0+1.f)*0.5f, i1 = (x1+1.f)*0.5f, i2 = (x2+1.f)*0.5f;
  m[i] = fminf(i0, fminf(i1, i2));
  g[i] = (0.2989f*x0 + 0.587f*x1 + 0.114f*x2 + 1.f)*0.5f;
}

// channel min of img/A
__global__ void k_chanmin2(const float* __restrict__ x, const float* __restrict__ A,
                           float* __restrict__ m2){
  int i = blockIdx.x*256 + threadIdx.x;
  int n = i >> 18;
  int hw = i & (HWSZ-1);
  const float* p = x + (size_t)n*3*HWSZ + hw;
  float ia0 = A[n*8+4], ia1 = A[n*8+5], ia2 = A[n*8+6];
  float v0 = (p[0]+1.f)*0.5f*ia0;
  float v1 = (p[HWSZ]+1.f)*0.5f*ia1;
  float v2 = (p[2*HWSZ]+1.f)*0.5f*ia2;
  m2[i] = fminf(v0, fminf(v1, v2));
}

// ---------------- 15-tap row min, OOB = 1.0 ----------------
__global__ void k_rowmin(const float* __restrict__ in, float* __restrict__ out){
  __shared__ float s[270];
  int bid = blockIdx.x;
  int x0 = (bid & 1)*256;
  int row = bid >> 1;              // 0 .. NIMG*HH-1
  int t = threadIdx.x;
  const float* r = in + (size_t)row*WW;
  int xa = x0 - 7 + t;
  s[t] = (xa >= 0 && xa < WW) ? r[xa] : 1.0f;
  if(t < 14){
    int xb = x0 + 249 + t;
    s[256+t] = (xb < WW) ? r[xb] : 1.0f;
  }
  __syncthreads();
  float v = s[t];
  #pragma unroll
  for(int d=1; d<15; ++d) v = fminf(v, s[t+d]);
  out[(size_t)row*WW + x0 + t] = v;
}

// ---------------- 15-tap col min, OOB = 1.0 ----------------
template<int MODE>   // 0: dark   1: trans = 1 - 0.95*min
__global__ void k_colmin(const float* __restrict__ in, float* __restrict__ out){
  int x = blockIdx.x*256 + threadIdx.x;
  int y = blockIdx.y;
  int n = blockIdx.z;
  const float* base = in + (size_t)n*HWSZ;
  float v = 3.0e38f;
  #pragma unroll
  for(int d=-7; d<=7; ++d){
    int yy = y + d;
    float tap = (yy >= 0 && yy < HH) ? base[(size_t)yy*WW + x] : 1.0f;
    v = fminf(v, tap);
  }
  float o = (MODE == 0) ? v : (1.0f - 0.95f*v);
  out[(size_t)n*HWSZ + (size_t)y*WW + x] = o;
}

// ---------------- utility: zero words ----------------
__global__ void k_zero(u32* __restrict__ p, int nwords){
  int i = blockIdx.x*256 + threadIdx.x;
  if(i < nwords) p[i] = 0;
}

// ---------------- selection: histogram bits [22:10] ----------------
__global__ void k_hist1(const float* __restrict__ dark, u32* __restrict__ hist1){
  __shared__ u32 h[8192];
  int n = blockIdx.x, part = blockIdx.y, t = threadIdx.x;  // 1024 threads
  for(int i=t; i<8192; i+=1024) h[i] = 0;
  __syncthreads();
  const u32* d = (const u32*)(dark + (size_t)n*HWSZ);
  int per = HWSZ/8, i0 = part*per;
  for(int i=i0+t; i<i0+per; i+=1024){
    u32 key = d[i];
    int b = (int)(key >> 10) - 0xFC000;
    b = max(0, min(8191, b));
    atomicAdd(&h[b], 1u);
  }
  __syncthreads();
  u32* gh = hist1 + n*8192;
  for(int i=t; i<8192; i+=1024) if(h[i]) atomicAdd(&gh[i], h[i]);
}

__device__ inline u32 block_scan_incl(u32 v, int t, u32* wsum){
  #pragma unroll
  for(int d=1; d<64; d<<=1){
    u32 u = __shfl_up(v, d);
    if((t & 63) >= d) v += u;
  }
  if((t & 63) == 63) wsum[t >> 6] = v;
  __syncthreads();
  u32 carry = 0;
  for(int w=0; w < (t >> 6); ++w) carry += wsum[w];
  return v + carry;
}

__global__ void k_csel1(const u32* __restrict__ hist1, u32* __restrict__ st){
  __shared__ u32 wsum[16];
  int n = blockIdx.x, t = threadIdx.x;   // 1024 threads, 8 bins each, descending
  const u32* hh = hist1 + n*8192;
  u32 loc[8]; u32 part = 0;
  #pragma unroll
  for(int k=0; k<8; ++k){
    loc[k] = hh[8191 - (t*8 + k)];
    part += loc[k];
  }
  u32 incl = block_scan_incl(part, t, wsum);
  u32 excl = incl - part;
  if(excl < TOPN && incl >= TOPN){
    u32 cum = excl;
    #pragma unroll
    for(int k=0; k<8; ++k){
      if(cum + loc[k] >= TOPN){
        st[n*16+0] = (u32)(8191 - (t*8+k));
        st[n*16+1] = cum;
        break;
      }
      cum += loc[k];
    }
  }
}

__global__ void k_hist2(const float* __restrict__ dark, const u32* __restrict__ st,
                        u32* __restrict__ hist2){
  __shared__ u32 h[1024];
  int n = blockIdx.x, part = blockIdx.y, t = threadIdx.x;
  h[t] = 0;
  __syncthreads();
  int bin_hi = (int)st[n*16+0];
  const u32* d = (const u32*)(dark + (size_t)n*HWSZ);
  int per = HWSZ/8, i0 = part*per;
  for(int i=i0+t; i<i0+per; i+=1024){
    u32 key = d[i];
    if(((int)(key >> 10) - 0xFC000) == bin_hi) atomicAdd(&h[key & 1023u], 1u);
  }
  __syncthreads();
  if(h[t]) atomicAdd(&hist2[n*1024 + t], h[t]);
}

__global__ void k_csel2(const u32* __restrict__ hist2, u32* __restrict__ st){
  __shared__ u32 wsum[16];
  int n = blockIdx.x, t = threadIdx.x;
  u32 bin_hi    = st[n*16+0];
  u32 cnt_above = st[n*16+1];
  u32 cnt = hist2[n*1024 + (1023 - t)];
  u32 incl = block_scan_incl(cnt, t, wsum);
  u32 excl = incl - cnt;
  u32 need = TOPN - cnt_above;
  if(excl < need && incl >= need){
    u32 lo = (u32)(1023 - t);
    u32 cnt_gt = cnt_above + excl;
    st[n*16+4] = ((bin_hi + 0xFC000u) << 10) | lo;
    st[n*16+5] = cnt_gt;
    st[n*16+6] = TOPN - cnt_gt;
  }
}

// sums over dark > v*, gather tie indices (dark == v*)
__global__ void k_sel4(const float* __restrict__ dark, const float* __restrict__ x,
                       u32* __restrict__ st, float* __restrict__ sums,
                       u32* __restrict__ ties){
  int n = blockIdx.x, part = blockIdx.y, t = threadIdx.x;
  u32 vb = st[n*16+4];
  const u32* d = (const u32*)(dark + (size_t)n*HWSZ);
  const float* xb = x + (size_t)n*3*HWSZ;
  float a0=0.f, a1=0.f, a2=0.f;
  int per = HWSZ/8, i0 = part*per;
  for(int i=i0+t; i<i0+per; i+=1024){
    u32 key = d[i];
    if(key > vb){
      a0 += xb[i]; a1 += xb[i+HWSZ]; a2 += xb[i+2*HWSZ];
    } else if(key == vb){
      u32 pos = atomicAdd(&st[n*16+7], 1u);
      if(pos < TIE_CAP) ties[n*TIE_CAP + pos] = (u32)i;
    }
  }
  __shared__ float red[1024];
  red[t]=a0; __syncthreads();
  for(int s=512;s>0;s>>=1){ if(t<s) red[t]+=red[t+s]; __syncthreads(); }
  if(t==0) atomicAdd(&sums[n*8+0], red[0]);
  __syncthreads();
  red[t]=a1; __syncthreads();
  for(int s=512;s>0;s>>=1){ if(t<s) red[t]+=red[t+s]; __syncthreads(); }
  if(t==0) atomicAdd(&sums[n*8+1], red[0]);
  __syncthreads();
  red[t]=a2; __syncthreads();
  for(int s=512;s>0;s>>=1){ if(t<s) red[t]+=red[t+s]; __syncthreads(); }
  if(t==0) atomicAdd(&sums[n*8+2], red[0]);
}

// resolve ties by smallest index (exact top_k semantics), finalize A and 1/A
__global__ void k_sel5(const float* __restrict__ x, const u32* __restrict__ st,
                       const float* __restrict__ sums, const u32* __restrict__ ties,
                       float* __restrict__ A){
  int n = blockIdx.x, t = threadIdx.x;   // 1024
  u32 k_need = st[n*16+6];
  u32 m = st[n*16+7]; if(m > TIE_CAP) m = TIE_CAP;
  const float* xb = x + (size_t)n*3*HWSZ;
  const u32* tb = ties + n*TIE_CAP;
  float a0=0.f, a1=0.f, a2=0.f;
  for(u32 e=t; e<m; e+=1024){
    u32 idx = tb[e];
    u32 rank = 0;
    for(u32 f=0; f<m; ++f) rank += (tb[f] < idx) ? 1u : 0u;
    if(rank < k_need){ a0 += xb[idx]; a1 += xb[idx+HWSZ]; a2 += xb[idx+2*HWSZ]; }
  }
  __shared__ float red[1024];
  __shared__ float fin[3];
  red[t]=a0; __syncthreads();
  for(int s=512;s>0;s>>=1){ if(t<s) red[t]+=red[t+s]; __syncthreads(); }
  if(t==0) fin[0]=red[0];
  __syncthreads();
  red[t]=a1; __syncthreads();
  for(int s=512;s>0;s>>=1){ if(t<s) red[t]+=red[t+s]; __syncthreads(); }
  if(t==0) fin[1]=red[0];
  __syncthreads();
  red[t]=a2; __syncthreads();
  for(int s=512;s>0;s>>=1){ if(t<s) red[t]+=red[t+s]; __syncthreads(); }
  if(t==0){
    fin[2]=red[0];
    for(int c=0;c<3;++c){
      float tot = sums[n*8+c] + fin[c];
      float Ac = (tot / 2621.0f + 1.0f) * 0.5f;   // mean of (x+1)/2
      A[n*8+c]   = Ac;
      A[n*8+4+c] = 1.0f / Ac;
    }
  }
}

// ---------------- horizontal 81-tap box sums (prefix scan per row) ----------------
__global__ void k_hbox4(const float* __restrict__ g, const float* __restrict__ p,
                        float* __restrict__ hI, float* __restrict__ hP,
                        float* __restrict__ hIp, float* __restrict__ hII){
  __shared__ float4 wsum[8];
  __shared__ float4 pref[512];
  int row = blockIdx.x;     // n*HH + y
  int t = threadIdx.x;      // 512
  size_t off = (size_t)row*WW + t;
  float I = g[off], P = p[off];
  float4 s; s.x = I; s.y = P; s.z = I*P; s.w = I*I;
  int lane = t & 63, wv = t >> 6;
  #pragma unroll
  for(int d=1; d<64; d<<=1){
    float ux=__shfl_up(s.x,d), uy=__shfl_up(s.y,d), uz=__shfl_up(s.z,d), uw=__shfl_up(s.w,d);
    if(lane >= d){ s.x+=ux; s.y+=uy; s.z+=uz; s.w+=uw; }
  }
  if(lane == 63) wsum[wv] = s;
  __syncthreads();
  float4 c = {0.f,0.f,0.f,0.f};
  for(int w=0; w<wv; ++w){ float4 q=wsum[w]; c.x+=q.x; c.y+=q.y; c.z+=q.z; c.w+=q.w; }
  s.x+=c.x; s.y+=c.y; s.z+=c.z; s.w+=c.w;
  pref[t] = s;
  __syncthreads();
  int hi = min(t+GR, WW-1);
  float4 S = pref[hi];
  if(t >= GR+1){ float4 L = pref[t-GR-1]; S.x-=L.x; S.y-=L.y; S.z-=L.z; S.w-=L.w; }
  hI[off]=S.x; hP[off]=S.y; hIp[off]=S.z; hII[off]=S.w;
}

__global__ void k_hbox2(const float* __restrict__ a, const float* __restrict__ b,
                        float* __restrict__ ha, float* __restrict__ hb){
  __shared__ float2 wsum[8];
  __shared__ float2 pref[512];
  int row = blockIdx.x, t = threadIdx.x;
  size_t off = (size_t)row*WW + t;
  float2 s; s.x = a[off]; s.y = b[off];
  int lane = t & 63, wv = t >> 6;
  #pragma unroll
  for(int d=1; d<64; d<<=1){
    float ux=__shfl_up(s.x,d), uy=__shfl_up(s.y,d);
    if(lane >= d){ s.x+=ux; s.y+=uy; }
  }
  if(lane == 63) wsum[wv] = s;
  __syncthreads();
  float2 c = {0.f,0.f};
  for(int w=0; w<wv; ++w){ float2 q=wsum[w]; c.x+=q.x; c.y+=q.y; }
  s.x+=c.x; s.y+=c.y;
  pref[t] = s;
  __syncthreads();
  int hi = min(t+GR, WW-1);
  float2 S = pref[hi];
  if(t >= GR+1){ float2 L = pref[t-GR-1]; S.x-=L.x; S.y-=L.y; }
  ha[off]=S.x; hb[off]=S.y;
}

// ---------------- vertical 81-tap running sums -> a,b ----------------
__global__ void k_vbox_ab(const float* __restrict__ hI, const float* __restrict__ hP,
                          const float* __restrict__ hIp, const float* __restrict__ hII,
                          float* __restrict__ a, float* __restrict__ b){
  int xc = blockIdx.x*256 + threadIdx.x;
  int n = blockIdx.z;
  int y0 = blockIdx.y*64;
  size_t base = (size_t)n*HWSZ + xc;
  float s0=0.f, s1=0.f, s2=0.f, s3=0.f;
  int ys = y0-GR; if(ys < 0) ys = 0;
  int ye = y0+GR; if(ye > HH-1) ye = HH-1;
  for(int y=ys; y<=ye; ++y){
    size_t o = base + (size_t)y*WW;
    s0+=hI[o]; s1+=hP[o]; s2+=hIp[o]; s3+=hII[o];
  }
  int nx = min(xc+GR, WW-1) - max(xc-GR, 0) + 1;
  for(int y=y0; y<y0+64; ++y){
    int ny = min(y+GR, HH-1) - max(y-GR, 0) + 1;
    float rc = 1.f/(float)(nx*ny);
    float mI=s0*rc, mP=s1*rc, mIp=s2*rc, mII=s3*rc;
    float va = (mIp - mI*mP) / (mII - mI*mI + 1e-3f);
    float vb = mP - va*mI;
    size_t o = base + (size_t)y*WW;
    a[o] = va; b[o] = vb;
    int ya = y+GR+1, yr = y-GR;
    if(ya < HH){ size_t oo = base+(size_t)ya*WW; s0+=hI[oo]; s1+=hP[oo]; s2+=hIp[oo]; s3+=hII[oo]; }
    if(yr >= 0){ size_t oo = base+(size_t)yr*WW; s0-=hI[oo]; s1-=hP[oo]; s2-=hIp[oo]; s3-=hII[oo]; }
  }
}

// ---------------- vertical sums of a,b -> T -> final composite ----------------
__global__ void k_final(const float* __restrict__ ha, const float* __restrict__ hb,
                        const float* __restrict__ g, const float* __restrict__ x,
                        const float* __restrict__ A, float* __restrict__ out){
  int xc = blockIdx.x*256 + threadIdx.x;
  int n = blockIdx.z;
  int y0 = blockIdx.y*32;
  float A0=A[n*8+0], A1=A[n*8+1], A2=A[n*8+2];
  size_t base = (size_t)n*HWSZ + xc;
  float sa=0.f, sb=0.f;
  int ys = y0-GR; if(ys < 0) ys = 0;
  int ye = y0+GR; if(ye > HH-1) ye = HH-1;
  for(int y=ys; y<=ye; ++y){
    size_t o = base + (size_t)y*WW;
    sa += ha[o]; sb += hb[o];
  }
  int nx = min(xc+GR, WW-1) - max(xc-GR, 0) + 1;
  const float* xb = x + (size_t)n*3*HWSZ;
  float* ob = out + (size_t)n*3*HWSZ;
  for(int y=y0; y<y0+32; ++y){
    int ny = min(y+GR, HH-1) - max(y-GR, 0) + 1;
    float rc = 1.f/(float)(nx*ny);
    size_t o = base + (size_t)y*WW;
    float T = sa*rc*g[o] + sb*rc;
    float rT = 1.0f / T;
    size_t oy = (size_t)y*WW + xc;
    float v0 = xb[oy], v1 = xb[oy+HWSZ], v2 = xb[oy+2*HWSZ];
    float i0=(v0+1.f)*0.5f, i1=(v1+1.f)*0.5f, i2=(v2+1.f)*0.5f;
    ob[oy]         = (i0-A0)*rT + A0;
    ob[oy+HWSZ]    = (i1-A1)*rT + A1;
    ob[oy+2*HWSZ]  = (i2-A2)*rT + A2;
    int ya = y+GR+1, yr = y-GR;
    if(ya < HH){ size_t oo = base+(size_t)ya*WW; sa+=ha[oo]; sb+=hb[oo]; }
    if(yr >= 0){ size_t oo = base+(size_t)yr*WW; sa-=ha[oo]; sb-=hb[oo]; }
  }
}

extern "C" void kernel_launch(void* const* d_in, const int* in_sizes, int n_in,
                              void* d_out, int out_size, void* d_ws, size_t ws_size,
                              hipStream_t stream) {
  const float* x = (const float*)d_in[0];
  float* out = (float*)d_out;
  char* ws = (char*)d_ws;

  const size_t NB = (size_t)NIMG*HWSZ*sizeof(float);   // 16 MiB per plane
  float* B0 = (float*)(ws + 0*NB);
  float* B1 = (float*)(ws + 1*NB);   // guidance
  float* B2 = (float*)(ws + 2*NB);
  float* B3 = (float*)(ws + 3*NB);
  float* B4 = (float*)(ws + 4*NB);
  float* B5 = (float*)(ws + 5*NB);
  // a,b intermediates live in d_out (overwritten by k_final which doesn't read them)
  float* aB = out;
  float* bB = out + (size_t)NIMG*HWSZ;

  char* sm = ws + 6*NB;
  u32* hist1 = (u32*)sm;                       // 512 KiB (reused as ties)
  u32* ties  = hist1;
  u32* hist2 = (u32*)(sm + 524288);            // 64 KiB
  u32* st    = (u32*)(sm + 524288 + 65536);    // 1 KiB
  float* sums= (float*)(sm + 524288 + 65536 + 1024);        // 512 B
  float* Abuf= (float*)(sm + 524288 + 65536 + 1024 + 512);  // 512 B

  // 1. channel min + guidance
  k_chanmin_guid<<<dim3((NIMG*HWSZ)/256), dim3(256), 0, stream>>>(x, B2, B1);
  // 2. dark channel (separable min-pool)
  k_rowmin<<<dim3(2*NIMG*HH), dim3(256), 0, stream>>>(B2, B3);
  k_colmin<0><<<dim3(2, HH, NIMG), dim3(256), 0, stream>>>(B3, B0);  // dark -> B0
  // 3. atmospheric light (exact top-2621 with index tie-break)
  int zwords = (524288 + 65536 + 1024 + 512) / 4;
  k_zero<<<dim3((zwords+255)/256), dim3(256), 0, stream>>>((u32*)sm, zwords);
  k_hist1<<<dim3(NIMG, 8), dim3(1024), 0, stream>>>(B0, hist1);
  k_csel1<<<dim3(NIMG), dim3(1024), 0, stream>>>(hist1, st);
  k_hist2<<<dim3(NIMG, 8), dim3(1024), 0, stream>>>(B0, st, hist2);
  k_csel2<<<dim3(NIMG), dim3(1024), 0, stream>>>(hist2, st);
  k_sel4<<<dim3(NIMG, 8), dim3(1024), 0, stream>>>(B0, x, st, sums, ties);
  k_sel5<<<dim3(NIMG), dim3(1024), 0, stream>>>(x, st, sums, ties, Abuf);
  // 4. transmission raw = 1 - 0.95 * dark(img/A)
  k_chanmin2<<<dim3((NIMG*HWSZ)/256), dim3(256), 0, stream>>>(x, Abuf, B2);
  k_rowmin<<<dim3(2*NIMG*HH), dim3(256), 0, stream>>>(B2, B3);
  k_colmin<1><<<dim3(2, HH, NIMG), dim3(256), 0, stream>>>(B3, B2);  // p -> B2
  // 5. guided filter round 1: box sums of I, p, Ip, II -> a, b
  k_hbox4<<<dim3(NIMG*HH), dim3(512), 0, stream>>>(B1, B2, B0, B3, B4, B5);
  k_vbox_ab<<<dim3(2, HH/64, NIMG), dim3(256), 0, stream>>>(B0, B3, B4, B5, aB, bB);
  // 6. guided filter round 2: box sums of a, b -> T -> final output
  k_hbox2<<<dim3(NIMG*HH), dim3(512), 0, stream>>>(aB, bB, B0, B3);
  k_final<<<dim3(2, HH/32, NIMG), dim3(256), 0, stream>>>(B0, B3, B1, x, Abuf, out);
}

// Round 2
// 299.885 us; speedup vs baseline: 1.1480x; 1.1480x over previous
//
#include <hip/hip_runtime.h>

typedef unsigned int u32;

#define NIMG 16
#define HH 512
#define WW 512
#define HWSZ (HH*WW)
#define TOPN 2621u
#define TIE_CAP 8192
#define GR 40

// ---------------- fused channel-min + 15-tap row min, OOB = 1.0 ----------------
template<int MODE>   // 0: plain (x+1)/2   1: (x+1)/2 / A
__global__ void k_rowmin_f(const float* __restrict__ x, const float* __restrict__ A,
                           float* __restrict__ out){
  __shared__ float s[270];
  int bid = blockIdx.x;
  int x0 = (bid & 1)*256;
  int row = bid >> 1;              // n*HH + y
  int n = row >> 9;
  int t = threadIdx.x;
  const float* xb = x + (size_t)n*3*HWSZ + (size_t)(row & 511)*WW;
  float ia0=1.f, ia1=1.f, ia2=1.f;
  if(MODE==1){ ia0=A[n*8+4]; ia1=A[n*8+5]; ia2=A[n*8+6]; }
  int xa = x0 - 7 + t;
  if(xa >= 0 && xa < WW){
    float v0=(xb[xa]+1.f)*0.5f*ia0;
    float v1=(xb[xa+HWSZ]+1.f)*0.5f*ia1;
    float v2=(xb[xa+2*HWSZ]+1.f)*0.5f*ia2;
    s[t] = fminf(v0,fminf(v1,v2));
  } else s[t] = 1.0f;
  if(t < 14){
    int xc = x0 + 249 + t;
    if(xc < WW){
      float v0=(xb[xc]+1.f)*0.5f*ia0;
      float v1=(xb[xc+HWSZ]+1.f)*0.5f*ia1;
      float v2=(xb[xc+2*HWSZ]+1.f)*0.5f*ia2;
      s[256+t] = fminf(v0,fminf(v1,v2));
    } else s[256+t] = 1.0f;
  }
  __syncthreads();
  float v = s[t];
  #pragma unroll
  for(int d=1; d<15; ++d) v = fminf(v, s[t+d]);
  out[(size_t)row*WW + x0 + t] = v;
}

// ---------------- 15-tap col min (float4), OOB = 1.0 ----------------
template<int MODE>   // 0: dark   1: trans = 1 - 0.95*min
__global__ void k_colmin(const float* __restrict__ in, float* __restrict__ out){
  int x4 = threadIdx.x;            // 128 threads = 512 floats
  int y = blockIdx.x;
  int n = blockIdx.y;
  const float4* base = (const float4*)(in + (size_t)n*HWSZ);
  float4 v = {3.0e38f,3.0e38f,3.0e38f,3.0e38f};
  #pragma unroll
  for(int d=-7; d<=7; ++d){
    int yy = y + d;
    if(yy >= 0 && yy < HH){
      float4 tp = base[(size_t)yy*(WW/4) + x4];
      v.x=fminf(v.x,tp.x); v.y=fminf(v.y,tp.y); v.z=fminf(v.z,tp.z); v.w=fminf(v.w,tp.w);
    } else {
      v.x=fminf(v.x,1.f); v.y=fminf(v.y,1.f); v.z=fminf(v.z,1.f); v.w=fminf(v.w,1.f);
    }
  }
  float4 o;
  if(MODE == 0) o = v;
  else { o.x=1.f-0.95f*v.x; o.y=1.f-0.95f*v.y; o.z=1.f-0.95f*v.z; o.w=1.f-0.95f*v.w; }
  ((float4*)(out + (size_t)n*HWSZ))[(size_t)y*(WW/4) + x4] = o;
}

// ---------------- utility: zero words ----------------
__global__ void k_zero(u32* __restrict__ p, int nwords){
  int i = blockIdx.x*256 + threadIdx.x;
  if(i < nwords) p[i] = 0;
}

// ---------------- selection: histogram bits [22:10] ----------------
__global__ void k_hist1(const float* __restrict__ dark, u32* __restrict__ hist1){
  __shared__ u32 h[8192];
  int n = blockIdx.x, part = blockIdx.y, t = threadIdx.x;  // 1024 threads
  for(int i=t; i<8192; i+=1024) h[i] = 0;
  __syncthreads();
  const u32* d = (const u32*)(dark + (size_t)n*HWSZ);
  int per = HWSZ/8, i0 = part*per;
  for(int i=i0+t; i<i0+per; i+=1024){
    u32 key = d[i];
    int b = (int)(key >> 10) - 0xFC000;
    b = max(0, min(8191, b));
    atomicAdd(&h[b], 1u);
  }
  __syncthreads();
  u32* gh = hist1 + n*8192;
  for(int i=t; i<8192; i+=1024) if(h[i]) atomicAdd(&gh[i], h[i]);
}

__device__ inline u32 block_scan_incl(u32 v, int t, u32* wsum){
  #pragma unroll
  for(int d=1; d<64; d<<=1){
    u32 u = __shfl_up(v, d);
    if((t & 63) >= d) v += u;
  }
  if((t & 63) == 63) wsum[t >> 6] = v;
  __syncthreads();
  u32 carry = 0;
  for(int w=0; w < (t >> 6); ++w) carry += wsum[w];
  return v + carry;
}

__global__ void k_csel1(const u32* __restrict__ hist1, u32* __restrict__ st){
  __shared__ u32 wsum[16];
  int n = blockIdx.x, t = threadIdx.x;
  const u32* hh = hist1 + n*8192;
  u32 loc[8]; u32 part = 0;
  #pragma unroll
  for(int k=0; k<8; ++k){
    loc[k] = hh[8191 - (t*8 + k)];
    part += loc[k];
  }
  u32 incl = block_scan_incl(part, t, wsum);
  u32 excl = incl - part;
  if(excl < TOPN && incl >= TOPN){
    u32 cum = excl;
    #pragma unroll
    for(int k=0; k<8; ++k){
      if(cum + loc[k] >= TOPN){
        st[n*16+0] = (u32)(8191 - (t*8+k));
        st[n*16+1] = cum;
        break;
      }
      cum += loc[k];
    }
  }
}

__global__ void k_hist2(const float* __restrict__ dark, const u32* __restrict__ st,
                        u32* __restrict__ hist2){
  __shared__ u32 h[1024];
  int n = blockIdx.x, part = blockIdx.y, t = threadIdx.x;
  h[t] = 0;
  __syncthreads();
  int bin_hi = (int)st[n*16+0];
  const u32* d = (const u32*)(dark + (size_t)n*HWSZ);
  int per = HWSZ/8, i0 = part*per;
  for(int i=i0+t; i<i0+per; i+=1024){
    u32 key = d[i];
    if(((int)(key >> 10) - 0xFC000) == bin_hi) atomicAdd(&h[key & 1023u], 1u);
  }
  __syncthreads();
  if(h[t]) atomicAdd(&hist2[n*1024 + t], h[t]);
}

__global__ void k_csel2(const u32* __restrict__ hist2, u32* __restrict__ st){
  __shared__ u32 wsum[16];
  int n = blockIdx.x, t = threadIdx.x;
  u32 bin_hi    = st[n*16+0];
  u32 cnt_above = st[n*16+1];
  u32 cnt = hist2[n*1024 + (1023 - t)];
  u32 incl = block_scan_incl(cnt, t, wsum);
  u32 excl = incl - cnt;
  u32 need = TOPN - cnt_above;
  if(excl < need && incl >= need){
    u32 lo = (u32)(1023 - t);
    u32 cnt_gt = cnt_above + excl;
    st[n*16+4] = ((bin_hi + 0xFC000u) << 10) | lo;
    st[n*16+5] = cnt_gt;
    st[n*16+6] = TOPN - cnt_gt;
  }
}

__global__ void k_sel4(const float* __restrict__ dark, const float* __restrict__ x,
                       u32* __restrict__ st, float* __restrict__ sums,
                       u32* __restrict__ ties){
  int n = blockIdx.x, part = blockIdx.y, t = threadIdx.x;
  u32 vb = st[n*16+4];
  const u32* d = (const u32*)(dark + (size_t)n*HWSZ);
  const float* xb = x + (size_t)n*3*HWSZ;
  float a0=0.f, a1=0.f, a2=0.f;
  int per = HWSZ/8, i0 = part*per;
  for(int i=i0+t; i<i0+per; i+=1024){
    u32 key = d[i];
    if(key > vb){
      a0 += xb[i]; a1 += xb[i+HWSZ]; a2 += xb[i+2*HWSZ];
    } else if(key == vb){
      u32 pos = atomicAdd(&st[n*16+7], 1u);
      if(pos < TIE_CAP) ties[n*TIE_CAP + pos] = (u32)i;
    }
  }
  __shared__ float red[1024];
  red[t]=a0; __syncthreads();
  for(int s=512;s>0;s>>=1){ if(t<s) red[t]+=red[t+s]; __syncthreads(); }
  if(t==0) atomicAdd(&sums[n*8+0], red[0]);
  __syncthreads();
  red[t]=a1; __syncthreads();
  for(int s=512;s>0;s>>=1){ if(t<s) red[t]+=red[t+s]; __syncthreads(); }
  if(t==0) atomicAdd(&sums[n*8+1], red[0]);
  __syncthreads();
  red[t]=a2; __syncthreads();
  for(int s=512;s>0;s>>=1){ if(t<s) red[t]+=red[t+s]; __syncthreads(); }
  if(t==0) atomicAdd(&sums[n*8+2], red[0]);
}

__global__ void k_sel5(const float* __restrict__ x, const u32* __restrict__ st,
                       const float* __restrict__ sums, const u32* __restrict__ ties,
                       float* __restrict__ A){
  int n = blockIdx.x, t = threadIdx.x;   // 1024
  u32 k_need = st[n*16+6];
  u32 m = st[n*16+7]; if(m > TIE_CAP) m = TIE_CAP;
  const float* xb = x + (size_t)n*3*HWSZ;
  const u32* tb = ties + n*TIE_CAP;
  float a0=0.f, a1=0.f, a2=0.f;
  for(u32 e=t; e<m; e+=1024){
    u32 idx = tb[e];
    u32 rank = 0;
    for(u32 f=0; f<m; ++f) rank += (tb[f] < idx) ? 1u : 0u;
    if(rank < k_need){ a0 += xb[idx]; a1 += xb[idx+HWSZ]; a2 += xb[idx+2*HWSZ]; }
  }
  __shared__ float red[1024];
  __shared__ float fin[3];
  red[t]=a0; __syncthreads();
  for(int s=512;s>0;s>>=1){ if(t<s) red[t]+=red[t+s]; __syncthreads(); }
  if(t==0) fin[0]=red[0];
  __syncthreads();
  red[t]=a1; __syncthreads();
  for(int s=512;s>0;s>>=1){ if(t<s) red[t]+=red[t+s]; __syncthreads(); }
  if(t==0) fin[1]=red[0];
  __syncthreads();
  red[t]=a2; __syncthreads();
  for(int s=512;s>0;s>>=1){ if(t<s) red[t]+=red[t+s]; __syncthreads(); }
  if(t==0){
    fin[2]=red[0];
    for(int c=0;c<3;++c){
      float tot = sums[n*8+c] + fin[c];
      float Ac = (tot / 2621.0f + 1.0f) * 0.5f;
      A[n*8+c]   = Ac;
      A[n*8+4+c] = 1.0f / Ac;
    }
  }
}

// -------- horizontal 81-tap box sums of I,p,Ip,II (guidance inline) -> float4 --------
__global__ void k_hbox4(const float* __restrict__ x, const float* __restrict__ p,
                        float4* __restrict__ h4){
  __shared__ float4 wsum[8];
  __shared__ float4 pref[512];
  int row = blockIdx.x;     // n*HH + y
  int n = row >> 9;
  int t = threadIdx.x;      // 512
  size_t off = (size_t)row*WW + t;
  const float* xb = x + (size_t)n*3*HWSZ + (size_t)(row & 511)*WW + t;
  float x0v = xb[0], x1v = xb[HWSZ], x2v = xb[2*HWSZ];
  float I = (0.2989f*x0v + 0.587f*x1v + 0.114f*x2v + 1.f)*0.5f;
  float P = p[off];
  float4 s; s.x = I; s.y = P; s.z = I*P; s.w = I*I;
  int lane = t & 63, wv = t >> 6;
  #pragma unroll
  for(int d=1; d<64; d<<=1){
    float ux=__shfl_up(s.x,d), uy=__shfl_up(s.y,d), uz=__shfl_up(s.z,d), uw=__shfl_up(s.w,d);
    if(lane >= d){ s.x+=ux; s.y+=uy; s.z+=uz; s.w+=uw; }
  }
  if(lane == 63) wsum[wv] = s;
  __syncthreads();
  float4 c = {0.f,0.f,0.f,0.f};
  for(int w=0; w<wv; ++w){ float4 q=wsum[w]; c.x+=q.x; c.y+=q.y; c.z+=q.z; c.w+=q.w; }
  s.x+=c.x; s.y+=c.y; s.z+=c.z; s.w+=c.w;
  pref[t] = s;
  __syncthreads();
  int hi = min(t+GR, WW-1);
  float4 S = pref[hi];
  if(t >= GR+1){ float4 L = pref[t-GR-1]; S.x-=L.x; S.y-=L.y; S.z-=L.z; S.w-=L.w; }
  h4[off] = S;
}

// -------- horizontal 81-tap box sums of (a,b) float2 -> float2 --------
__global__ void k_hbox2(const float2* __restrict__ ab, float2* __restrict__ hab){
  __shared__ float2 wsum[8];
  __shared__ float2 pref[512];
  int row = blockIdx.x, t = threadIdx.x;
  size_t off = (size_t)row*WW + t;
  float2 s = ab[off];
  int lane = t & 63, wv = t >> 6;
  #pragma unroll
  for(int d=1; d<64; d<<=1){
    float ux=__shfl_up(s.x,d), uy=__shfl_up(s.y,d);
    if(lane >= d){ s.x+=ux; s.y+=uy; }
  }
  if(lane == 63) wsum[wv] = s;
  __syncthreads();
  float2 c = {0.f,0.f};
  for(int w=0; w<wv; ++w){ float2 q=wsum[w]; c.x+=q.x; c.y+=q.y; }
  s.x+=c.x; s.y+=c.y;
  pref[t] = s;
  __syncthreads();
  int hi = min(t+GR, WW-1);
  float2 S = pref[hi];
  if(t >= GR+1){ float2 L = pref[t-GR-1]; S.x-=L.x; S.y-=L.y; }
  hab[off]=S;
}

// ---------------- vertical 81-tap running sums (float4) -> a,b (float2) ----------------
__global__ void k_vbox_ab(const float4* __restrict__ h4, float2* __restrict__ ab){
  int xc = blockIdx.x*256 + threadIdx.x;
  int n = blockIdx.z;
  int y0 = blockIdx.y*16;
  const float4* hb = h4 + (size_t)n*HWSZ;
  float s0=0.f, s1=0.f, s2=0.f, s3=0.f;
  int ys = y0-GR; if(ys < 0) ys = 0;
  int ye = y0+GR; if(ye > HH-1) ye = HH-1;
  #pragma unroll 4
  for(int y=ys; y<=ye; ++y){
    float4 v = hb[(size_t)y*WW + xc];
    s0+=v.x; s1+=v.y; s2+=v.z; s3+=v.w;
  }
  int nx = min(xc+GR, WW-1) - max(xc-GR, 0) + 1;
  float2* abb = ab + (size_t)n*HWSZ;
  #pragma unroll
  for(int k=0; k<16; ++k){
    int y = y0 + k;
    int ny = min(y+GR, HH-1) - max(y-GR, 0) + 1;
    float rc = 1.f/(float)(nx*ny);
    float mI=s0*rc, mP=s1*rc, mIp=s2*rc, mII=s3*rc;
    float va = (mIp - mI*mP) / (mII - mI*mI + 1e-3f);
    float vb = mP - va*mI;
    abb[(size_t)y*WW + xc] = make_float2(va, vb);
    int ya = y+GR+1, yr = y-GR;
    if(ya < HH){ float4 v = hb[(size_t)ya*WW + xc]; s0+=v.x; s1+=v.y; s2+=v.z; s3+=v.w; }
    if(yr >= 0){ float4 v = hb[(size_t)yr*WW + xc]; s0-=v.x; s1-=v.y; s2-=v.z; s3-=v.w; }
  }
}

// ---------------- vertical sums of (a,b) -> T -> final composite ----------------
__global__ void k_final(const float2* __restrict__ hab, const float* __restrict__ x,
                        const float* __restrict__ A, float* __restrict__ out){
  int xc = blockIdx.x*256 + threadIdx.x;
  int n = blockIdx.z;
  int y0 = blockIdx.y*16;
  float A0=A[n*8+0], A1=A[n*8+1], A2=A[n*8+2];
  const float2* hb = hab + (size_t)n*HWSZ;
  float sa=0.f, sb=0.f;
  int ys = y0-GR; if(ys < 0) ys = 0;
  int ye = y0+GR; if(ye > HH-1) ye = HH-1;
  #pragma unroll 4
  for(int y=ys; y<=ye; ++y){
    float2 v = hb[(size_t)y*WW + xc];
    sa += v.x; sb += v.y;
  }
  int nx = min(xc+GR, WW-1) - max(xc-GR, 0) + 1;
  const float* xb = x + (size_t)n*3*HWSZ;
  float* ob = out + (size_t)n*3*HWSZ;
  #pragma unroll
  for(int k=0; k<16; ++k){
    int y = y0 + k;
    int ny = min(y+GR, HH-1) - max(y-GR, 0) + 1;
    float rc = 1.f/(float)(nx*ny);
    size_t oy = (size_t)y*WW + xc;
    float v0 = xb[oy], v1 = xb[oy+HWSZ], v2 = xb[oy+2*HWSZ];
    float g = (0.2989f*v0 + 0.587f*v1 + 0.114f*v2 + 1.f)*0.5f;
    float T = (sa*g + sb)*rc;
    float rT = 1.0f / T;
    float i0=(v0+1.f)*0.5f, i1=(v1+1.f)*0.5f, i2=(v2+1.f)*0.5f;
    ob[oy]        = (i0-A0)*rT + A0;
    ob[oy+HWSZ]   = (i1-A1)*rT + A1;
    ob[oy+2*HWSZ] = (i2-A2)*rT + A2;
    int ya = y+GR+1, yr = y-GR;
    if(ya < HH){ float2 v = hb[(size_t)ya*WW + xc]; sa+=v.x; sb+=v.y; }
    if(yr >= 0){ float2 v = hb[(size_t)yr*WW + xc]; sa-=v.x; sb-=v.y; }
  }
}

extern "C" void kernel_launch(void* const* d_in, const int* in_sizes, int n_in,
                              void* d_out, int out_size, void* d_ws, size_t ws_size,
                              hipStream_t stream) {
  const float* x = (const float*)d_in[0];
  float* out = (float*)d_out;
  char* ws = (char*)d_ws;

  const size_t NB = (size_t)NIMG*HWSZ*sizeof(float);   // 16 MiB per plane

  float* rowtmp = (float*)(ws + 0*NB);        // 16 MiB   (dead before h4 is written)
  float* dark   = (float*)(ws + 1*NB);        // 16 MiB   (dead before h4 is written)
  float4* h4    = (float4*)(ws + 0*NB);       // 64 MiB   (planes 0-3)
  float2* hab   = (float2*)(ws + 0*NB);       // 32 MiB   (after h4 dead)
  float* pT     = (float*)(ws + 4*NB);        // 16 MiB   trans_raw
  float2* ab    = (float2*)out;               // 32 MiB of d_out (overwritten by k_final)

  char* sm = ws + 5*NB;
  u32* hist1 = (u32*)sm;                       // 512 KiB (reused as ties)
  u32* ties  = hist1;
  u32* hist2 = (u32*)(sm + 524288);            // 64 KiB
  u32* st    = (u32*)(sm + 524288 + 65536);    // 1 KiB
  float* sums= (float*)(sm + 524288 + 65536 + 1024);
  float* Abuf= (float*)(sm + 524288 + 65536 + 1024 + 512);

  // 1. dark channel (fused channel-min + separable min-pool)
  k_rowmin_f<0><<<dim3(2*NIMG*HH), dim3(256), 0, stream>>>(x, nullptr, rowtmp);
  k_colmin<0><<<dim3(HH, NIMG), dim3(128), 0, stream>>>(rowtmp, dark);
  // 2. atmospheric light (exact top-2621 with index tie-break)
  int zwords = (524288 + 65536 + 1024 + 512) / 4;
  k_zero<<<dim3((zwords+255)/256), dim3(256), 0, stream>>>((u32*)sm, zwords);
  k_hist1<<<dim3(NIMG, 8), dim3(1024), 0, stream>>>(dark, hist1);
  k_csel1<<<dim3(NIMG), dim3(1024), 0, stream>>>(hist1, st);
  k_hist2<<<dim3(NIMG, 8), dim3(1024), 0, stream>>>(dark, st, hist2);
  k_csel2<<<dim3(NIMG), dim3(1024), 0, stream>>>(hist2, st);
  k_sel4<<<dim3(NIMG, 8), dim3(1024), 0, stream>>>(dark, x, st, sums, ties);
  k_sel5<<<dim3(NIMG), dim3(1024), 0, stream>>>(x, st, sums, ties, Abuf);
  // 3. transmission raw = 1 - 0.95 * dark(img/A)
  k_rowmin_f<1><<<dim3(2*NIMG*HH), dim3(256), 0, stream>>>(x, Abuf, rowtmp);
  k_colmin<1><<<dim3(HH, NIMG), dim3(128), 0, stream>>>(rowtmp, pT);
  // 4. guided filter round 1 (guidance computed inline from x)
  k_hbox4<<<dim3(NIMG*HH), dim3(512), 0, stream>>>(x, pT, h4);
  k_vbox_ab<<<dim3(2, HH/16, NIMG), dim3(256), 0, stream>>>(h4, ab);
  // 5. guided filter round 2 -> T -> final output
  k_hbox2<<<dim3(NIMG*HH), dim3(512), 0, stream>>>(ab, hab);
  k_final<<<dim3(2, HH/16, NIMG), dim3(256), 0, stream>>>(hab, x, Abuf, out);
}

// Round 3
// 276.049 us; speedup vs baseline: 1.2472x; 1.0863x over previous
//
#include <hip/hip_runtime.h>
#include <hip/hip_fp16.h>

typedef unsigned int u32;

#define NIMG 16
#define HH 512
#define WW 512
#define HWSZ (HH*WW)
#define TOPN 2621u
#define TIE_CAP 8192
#define GR 40

// ---------- f16 packing helpers ----------
static __device__ inline uint2 pack_h4(float4 S){
  __half2 lo = __floats2half2_rn(S.x, S.y);
  __half2 hi = __floats2half2_rn(S.z, S.w);
  uint2 r;
  r.x = *reinterpret_cast<unsigned int*>(&lo);
  r.y = *reinterpret_cast<unsigned int*>(&hi);
  return r;
}
static __device__ inline float4 unpack_h4(uint2 v){
  __half2 lo = *reinterpret_cast<__half2*>(&v.x);
  __half2 hi = *reinterpret_cast<__half2*>(&v.y);
  float2 A = __half22float2(lo), B = __half22float2(hi);
  return make_float4(A.x, A.y, B.x, B.y);
}
static __device__ inline u32 pack_h2(float a, float b){
  __half2 h = __floats2half2_rn(a, b);
  return *reinterpret_cast<unsigned int*>(&h);
}
static __device__ inline float2 unpack_h2(u32 v){
  __half2 h = *reinterpret_cast<__half2*>(&v);
  return __half22float2(h);
}

// ---------------- fused channel-min + 15-tap row min, OOB = 1.0 ----------------
template<int MODE>   // 0: plain (x+1)/2   1: (x+1)/2 / A
__global__ void k_rowmin_f(const float* __restrict__ x, const float* __restrict__ A,
                           float* __restrict__ out){
  __shared__ float s[270];
  int bid = blockIdx.x;
  int x0 = (bid & 1)*256;
  int row = bid >> 1;              // n*HH + y
  int n = row >> 9;
  int t = threadIdx.x;
  const float* xb = x + (size_t)n*3*HWSZ + (size_t)(row & 511)*WW;
  float ia0=1.f, ia1=1.f, ia2=1.f;
  if(MODE==1){ ia0=A[n*8+4]; ia1=A[n*8+5]; ia2=A[n*8+6]; }
  int xa = x0 - 7 + t;
  if(xa >= 0 && xa < WW){
    float v0=(xb[xa]+1.f)*0.5f*ia0;
    float v1=(xb[xa+HWSZ]+1.f)*0.5f*ia1;
    float v2=(xb[xa+2*HWSZ]+1.f)*0.5f*ia2;
    s[t] = fminf(v0,fminf(v1,v2));
  } else s[t] = 1.0f;
  if(t < 14){
    int xc = x0 + 249 + t;
    if(xc < WW){
      float v0=(xb[xc]+1.f)*0.5f*ia0;
      float v1=(xb[xc+HWSZ]+1.f)*0.5f*ia1;
      float v2=(xb[xc+2*HWSZ]+1.f)*0.5f*ia2;
      s[256+t] = fminf(v0,fminf(v1,v2));
    } else s[256+t] = 1.0f;
  }
  __syncthreads();
  float v = s[t];
  #pragma unroll
  for(int d=1; d<15; ++d) v = fminf(v, s[t+d]);
  out[(size_t)row*WW + x0 + t] = v;
}

// ---------------- 15-tap col min (float4), OOB = 1.0 ----------------
template<int MODE>   // 0: dark   1: trans = 1 - 0.95*min
__global__ void k_colmin(const float* __restrict__ in, float* __restrict__ out){
  int x4 = threadIdx.x;            // 128 threads = 512 floats
  int y = blockIdx.x;
  int n = blockIdx.y;
  const float4* base = (const float4*)(in + (size_t)n*HWSZ);
  float4 v = {3.0e38f,3.0e38f,3.0e38f,3.0e38f};
  #pragma unroll
  for(int d=-7; d<=7; ++d){
    int yy = y + d;
    if(yy >= 0 && yy < HH){
      float4 tp = base[(size_t)yy*(WW/4) + x4];
      v.x=fminf(v.x,tp.x); v.y=fminf(v.y,tp.y); v.z=fminf(v.z,tp.z); v.w=fminf(v.w,tp.w);
    } else {
      v.x=fminf(v.x,1.f); v.y=fminf(v.y,1.f); v.z=fminf(v.z,1.f); v.w=fminf(v.w,1.f);
    }
  }
  float4 o;
  if(MODE == 0) o = v;
  else { o.x=1.f-0.95f*v.x; o.y=1.f-0.95f*v.y; o.z=1.f-0.95f*v.z; o.w=1.f-0.95f*v.w; }
  ((float4*)(out + (size_t)n*HWSZ))[(size_t)y*(WW/4) + x4] = o;
}

// ---------------- utility: zero words ----------------
__global__ void k_zero(u32* __restrict__ p, int nwords){
  int i = blockIdx.x*256 + threadIdx.x;
  if(i < nwords) p[i] = 0;
}

// ---------------- selection: histogram bits [22:10] ----------------
__global__ void k_hist1(const float* __restrict__ dark, u32* __restrict__ hist1){
  __shared__ u32 h[8192];
  int n = blockIdx.x, part = blockIdx.y, t = threadIdx.x;  // 1024 threads
  for(int i=t; i<8192; i+=1024) h[i] = 0;
  __syncthreads();
  const u32* d = (const u32*)(dark + (size_t)n*HWSZ);
  int per = HWSZ/8, i0 = part*per;
  for(int i=i0+t; i<i0+per; i+=1024){
    u32 key = d[i];
    int b = (int)(key >> 10) - 0xFC000;
    b = max(0, min(8191, b));
    atomicAdd(&h[b], 1u);
  }
  __syncthreads();
  u32* gh = hist1 + n*8192;
  for(int i=t; i<8192; i+=1024) if(h[i]) atomicAdd(&gh[i], h[i]);
}

__device__ inline u32 block_scan_incl(u32 v, int t, u32* wsum){
  #pragma unroll
  for(int d=1; d<64; d<<=1){
    u32 u = __shfl_up(v, d);
    if((t & 63) >= d) v += u;
  }
  if((t & 63) == 63) wsum[t >> 6] = v;
  __syncthreads();
  u32 carry = 0;
  for(int w=0; w < (t >> 6); ++w) carry += wsum[w];
  return v + carry;
}

__global__ void k_csel1(const u32* __restrict__ hist1, u32* __restrict__ st){
  __shared__ u32 wsum[16];
  int n = blockIdx.x, t = threadIdx.x;
  const u32* hh = hist1 + n*8192;
  u32 loc[8]; u32 part = 0;
  #pragma unroll
  for(int k=0; k<8; ++k){
    loc[k] = hh[8191 - (t*8 + k)];
    part += loc[k];
  }
  u32 incl = block_scan_incl(part, t, wsum);
  u32 excl = incl - part;
  if(excl < TOPN && incl >= TOPN){
    u32 cum = excl;
    #pragma unroll
    for(int k=0; k<8; ++k){
      if(cum + loc[k] >= TOPN){
        st[n*16+0] = (u32)(8191 - (t*8+k));
        st[n*16+1] = cum;
        break;
      }
      cum += loc[k];
    }
  }
}

__global__ void k_hist2(const float* __restrict__ dark, const u32* __restrict__ st,
                        u32* __restrict__ hist2){
  __shared__ u32 h[1024];
  int n = blockIdx.x, part = blockIdx.y, t = threadIdx.x;
  h[t] = 0;
  __syncthreads();
  int bin_hi = (int)st[n*16+0];
  const u32* d = (const u32*)(dark + (size_t)n*HWSZ);
  int per = HWSZ/8, i0 = part*per;
  for(int i=i0+t; i<i0+per; i+=1024){
    u32 key = d[i];
    if(((int)(key >> 10) - 0xFC000) == bin_hi) atomicAdd(&h[key & 1023u], 1u);
  }
  __syncthreads();
  if(h[t]) atomicAdd(&hist2[n*1024 + t], h[t]);
}

__global__ void k_csel2(const u32* __restrict__ hist2, u32* __restrict__ st){
  __shared__ u32 wsum[16];
  int n = blockIdx.x, t = threadIdx.x;
  u32 bin_hi    = st[n*16+0];
  u32 cnt_above = st[n*16+1];
  u32 cnt = hist2[n*1024 + (1023 - t)];
  u32 incl = block_scan_incl(cnt, t, wsum);
  u32 excl = incl - cnt;
  u32 need = TOPN - cnt_above;
  if(excl < need && incl >= need){
    u32 lo = (u32)(1023 - t);
    u32 cnt_gt = cnt_above + excl;
    st[n*16+4] = ((bin_hi + 0xFC000u) << 10) | lo;
    st[n*16+5] = cnt_gt;
    st[n*16+6] = TOPN - cnt_gt;
  }
}

__global__ void k_sel4(const float* __restrict__ dark, const float* __restrict__ x,
                       u32* __restrict__ st, float* __restrict__ sums,
                       u32* __restrict__ ties){
  int n = blockIdx.x, part = blockIdx.y, t = threadIdx.x;
  u32 vb = st[n*16+4];
  const u32* d = (const u32*)(dark + (size_t)n*HWSZ);
  const float* xb = x + (size_t)n*3*HWSZ;
  float a0=0.f, a1=0.f, a2=0.f;
  int per = HWSZ/8, i0 = part*per;
  for(int i=i0+t; i<i0+per; i+=1024){
    u32 key = d[i];
    if(key > vb){
      a0 += xb[i]; a1 += xb[i+HWSZ]; a2 += xb[i+2*HWSZ];
    } else if(key == vb){
      u32 pos = atomicAdd(&st[n*16+7], 1u);
      if(pos < TIE_CAP) ties[n*TIE_CAP + pos] = (u32)i;
    }
  }
  __shared__ float red[1024];
  red[t]=a0; __syncthreads();
  for(int s=512;s>0;s>>=1){ if(t<s) red[t]+=red[t+s]; __syncthreads(); }
  if(t==0) atomicAdd(&sums[n*8+0], red[0]);
  __syncthreads();
  red[t]=a1; __syncthreads();
  for(int s=512;s>0;s>>=1){ if(t<s) red[t]+=red[t+s]; __syncthreads(); }
  if(t==0) atomicAdd(&sums[n*8+1], red[0]);
  __syncthreads();
  red[t]=a2; __syncthreads();
  for(int s=512;s>0;s>>=1){ if(t<s) red[t]+=red[t+s]; __syncthreads(); }
  if(t==0) atomicAdd(&sums[n*8+2], red[0]);
}

__global__ void k_sel5(const float* __restrict__ x, const u32* __restrict__ st,
                       const float* __restrict__ sums, const u32* __restrict__ ties,
                       float* __restrict__ A){
  int n = blockIdx.x, t = threadIdx.x;   // 1024
  u32 k_need = st[n*16+6];
  u32 m = st[n*16+7]; if(m > TIE_CAP) m = TIE_CAP;
  const float* xb = x + (size_t)n*3*HWSZ;
  const u32* tb = ties + n*TIE_CAP;
  float a0=0.f, a1=0.f, a2=0.f;
  for(u32 e=t; e<m; e+=1024){
    u32 idx = tb[e];
    u32 rank = 0;
    for(u32 f=0; f<m; ++f) rank += (tb[f] < idx) ? 1u : 0u;
    if(rank < k_need){ a0 += xb[idx]; a1 += xb[idx+HWSZ]; a2 += xb[idx+2*HWSZ]; }
  }
  __shared__ float red[1024];
  __shared__ float fin[3];
  red[t]=a0; __syncthreads();
  for(int s=512;s>0;s>>=1){ if(t<s) red[t]+=red[t+s]; __syncthreads(); }
  if(t==0) fin[0]=red[0];
  __syncthreads();
  red[t]=a1; __syncthreads();
  for(int s=512;s>0;s>>=1){ if(t<s) red[t]+=red[t+s]; __syncthreads(); }
  if(t==0) fin[1]=red[0];
  __syncthreads();
  red[t]=a2; __syncthreads();
  for(int s=512;s>0;s>>=1){ if(t<s) red[t]+=red[t+s]; __syncthreads(); }
  if(t==0){
    fin[2]=red[0];
    for(int c=0;c<3;++c){
      float tot = sums[n*8+c] + fin[c];
      float Ac = (tot / 2621.0f + 1.0f) * 0.5f;
      A[n*8+c]   = Ac;
      A[n*8+4+c] = 1.0f / Ac;
    }
  }
}

// -------- horizontal 81-tap box sums of I,p,Ip,II (guidance inline) -> packed f16x4 --------
__global__ void k_hbox4(const float* __restrict__ x, const float* __restrict__ p,
                        uint2* __restrict__ h4){
  __shared__ float4 wsum[8];
  __shared__ float4 pref[512];
  int row = blockIdx.x;     // n*HH + y
  int n = row >> 9;
  int t = threadIdx.x;      // 512
  size_t off = (size_t)row*WW + t;
  const float* xb = x + (size_t)n*3*HWSZ + (size_t)(row & 511)*WW + t;
  float x0v = xb[0], x1v = xb[HWSZ], x2v = xb[2*HWSZ];
  float I = (0.2989f*x0v + 0.587f*x1v + 0.114f*x2v + 1.f)*0.5f;
  float P = p[off];
  float4 s; s.x = I; s.y = P; s.z = I*P; s.w = I*I;
  int lane = t & 63, wv = t >> 6;
  #pragma unroll
  for(int d=1; d<64; d<<=1){
    float ux=__shfl_up(s.x,d), uy=__shfl_up(s.y,d), uz=__shfl_up(s.z,d), uw=__shfl_up(s.w,d);
    if(lane >= d){ s.x+=ux; s.y+=uy; s.z+=uz; s.w+=uw; }
  }
  if(lane == 63) wsum[wv] = s;
  __syncthreads();
  float4 c = {0.f,0.f,0.f,0.f};
  for(int w=0; w<wv; ++w){ float4 q=wsum[w]; c.x+=q.x; c.y+=q.y; c.z+=q.z; c.w+=q.w; }
  s.x+=c.x; s.y+=c.y; s.z+=c.z; s.w+=c.w;
  pref[t] = s;
  __syncthreads();
  int hi = min(t+GR, WW-1);
  float4 S = pref[hi];
  if(t >= GR+1){ float4 L = pref[t-GR-1]; S.x-=L.x; S.y-=L.y; S.z-=L.z; S.w-=L.w; }
  h4[off] = pack_h4(S);
}

// -------- horizontal 81-tap box sums of (a,b) float2 -> packed f16x2 --------
__global__ void k_hbox2(const float2* __restrict__ ab, u32* __restrict__ hab){
  __shared__ float2 wsum[8];
  __shared__ float2 pref[512];
  int row = blockIdx.x, t = threadIdx.x;
  size_t off = (size_t)row*WW + t;
  float2 s = ab[off];
  int lane = t & 63, wv = t >> 6;
  #pragma unroll
  for(int d=1; d<64; d<<=1){
    float ux=__shfl_up(s.x,d), uy=__shfl_up(s.y,d);
    if(lane >= d){ s.x+=ux; s.y+=uy; }
  }
  if(lane == 63) wsum[wv] = s;
  __syncthreads();
  float2 c = {0.f,0.f};
  for(int w=0; w<wv; ++w){ float2 q=wsum[w]; c.x+=q.x; c.y+=q.y; }
  s.x+=c.x; s.y+=c.y;
  pref[t] = s;
  __syncthreads();
  int hi = min(t+GR, WW-1);
  float2 S = pref[hi];
  if(t >= GR+1){ float2 L = pref[t-GR-1]; S.x-=L.x; S.y-=L.y; }
  hab[off] = pack_h2(S.x, S.y);
}

// ---------------- vertical 81-tap running sums (f16x4) -> a,b (float2) ----------------
__global__ void k_vbox_ab(const uint2* __restrict__ h4, float2* __restrict__ ab){
  int xc = blockIdx.x*256 + threadIdx.x;
  int n = blockIdx.z;
  int y0 = blockIdx.y*16;
  const uint2* hb = h4 + (size_t)n*HWSZ;
  float s0=0.f, s1=0.f, s2=0.f, s3=0.f;
  int nx = min(xc+GR, WW-1) - max(xc-GR, 0) + 1;
  float2* abb = ab + (size_t)n*HWSZ;

  if(y0 >= 48 && y0 <= 448){
    // interior: no clamps anywhere
    #pragma unroll 3
    for(int y=y0-GR; y<=y0+GR; ++y){
      float4 v = unpack_h4(hb[(size_t)y*WW + xc]);
      s0+=v.x; s1+=v.y; s2+=v.z; s3+=v.w;
    }
    #pragma unroll
    for(int g=0; g<4; ++g){
      uint2 ad[4], sb[4];
      #pragma unroll
      for(int j=0; j<4; ++j){
        int y = y0 + g*4 + j;
        ad[j] = hb[(size_t)(y+GR+1)*WW + xc];
        sb[j] = hb[(size_t)(y-GR)*WW + xc];
      }
      #pragma unroll
      for(int j=0; j<4; ++j){
        int y = y0 + g*4 + j;
        int ny = min(y+GR, HH-1) - max(y-GR, 0) + 1;
        float rc = 1.f/(float)(nx*ny);
        float mI=s0*rc, mP=s1*rc, mIp=s2*rc, mII=s3*rc;
        float va = (mIp - mI*mP) / (mII - mI*mI + 1e-3f);
        float vb = mP - va*mI;
        abb[(size_t)y*WW + xc] = make_float2(va, vb);
        float4 fa = unpack_h4(ad[j]), fs = unpack_h4(sb[j]);
        s0 += fa.x - fs.x; s1 += fa.y - fs.y; s2 += fa.z - fs.z; s3 += fa.w - fs.w;
      }
    }
  } else {
    int ys = y0-GR; if(ys < 0) ys = 0;
    int ye = y0+GR; if(ye > HH-1) ye = HH-1;
    for(int y=ys; y<=ye; ++y){
      float4 v = unpack_h4(hb[(size_t)y*WW + xc]);
      s0+=v.x; s1+=v.y; s2+=v.z; s3+=v.w;
    }
    #pragma unroll
    for(int k=0; k<16; ++k){
      int y = y0 + k;
      int ny = min(y+GR, HH-1) - max(y-GR, 0) + 1;
      float rc = 1.f/(float)(nx*ny);
      float mI=s0*rc, mP=s1*rc, mIp=s2*rc, mII=s3*rc;
      float va = (mIp - mI*mP) / (mII - mI*mI + 1e-3f);
      float vb = mP - va*mI;
      abb[(size_t)y*WW + xc] = make_float2(va, vb);
      int ya = y+GR+1, yr = y-GR;
      if(ya < HH){ float4 v = unpack_h4(hb[(size_t)ya*WW + xc]); s0+=v.x; s1+=v.y; s2+=v.z; s3+=v.w; }
      if(yr >= 0){ float4 v = unpack_h4(hb[(size_t)yr*WW + xc]); s0-=v.x; s1-=v.y; s2-=v.z; s3-=v.w; }
    }
  }
}

// ---------------- vertical sums of (a,b) f16x2 -> T -> final composite ----------------
__global__ void k_final(const u32* __restrict__ hab, const float* __restrict__ x,
                        const float* __restrict__ A, float* __restrict__ out){
  int xc = blockIdx.x*256 + threadIdx.x;
  int n = blockIdx.z;
  int y0 = blockIdx.y*16;
  float A0=A[n*8+0], A1=A[n*8+1], A2=A[n*8+2];
  const u32* hb = hab + (size_t)n*HWSZ;
  float sa=0.f, sb=0.f;
  int nx = min(xc+GR, WW-1) - max(xc-GR, 0) + 1;
  const float* xb = x + (size_t)n*3*HWSZ;
  float* ob = out + (size_t)n*3*HWSZ;

  if(y0 >= 48 && y0 <= 448){
    #pragma unroll 3
    for(int y=y0-GR; y<=y0+GR; ++y){
      float2 v = unpack_h2(hb[(size_t)y*WW + xc]);
      sa += v.x; sb += v.y;
    }
    #pragma unroll
    for(int g=0; g<4; ++g){
      u32 ad[4], su[4];
      #pragma unroll
      for(int j=0; j<4; ++j){
        int y = y0 + g*4 + j;
        ad[j] = hb[(size_t)(y+GR+1)*WW + xc];
        su[j] = hb[(size_t)(y-GR)*WW + xc];
      }
      #pragma unroll
      for(int j=0; j<4; ++j){
        int y = y0 + g*4 + j;
        int ny = min(y+GR, HH-1) - max(y-GR, 0) + 1;
        float rc = 1.f/(float)(nx*ny);
        size_t oy = (size_t)y*WW + xc;
        float v0 = xb[oy], v1 = xb[oy+HWSZ], v2 = xb[oy+2*HWSZ];
        float g2 = (0.2989f*v0 + 0.587f*v1 + 0.114f*v2 + 1.f)*0.5f;
        float T = (sa*g2 + sb)*rc;
        float rT = 1.0f / T;
        float i0=(v0+1.f)*0.5f, i1=(v1+1.f)*0.5f, i2=(v2+1.f)*0.5f;
        __builtin_nontemporal_store((i0-A0)*rT + A0, &ob[oy]);
        __builtin_nontemporal_store((i1-A1)*rT + A1, &ob[oy+HWSZ]);
        __builtin_nontemporal_store((i2-A2)*rT + A2, &ob[oy+2*HWSZ]);
        float2 fa = unpack_h2(ad[j]), fs = unpack_h2(su[j]);
        sa += fa.x - fs.x; sb += fa.y - fs.y;
      }
    }
  } else {
    int ys = y0-GR; if(ys < 0) ys = 0;
    int ye = y0+GR; if(ye > HH-1) ye = HH-1;
    for(int y=ys; y<=ye; ++y){
      float2 v = unpack_h2(hb[(size_t)y*WW + xc]);
      sa += v.x; sb += v.y;
    }
    #pragma unroll
    for(int k=0; k<16; ++k){
      int y = y0 + k;
      int ny = min(y+GR, HH-1) - max(y-GR, 0) + 1;
      float rc = 1.f/(float)(nx*ny);
      size_t oy = (size_t)y*WW + xc;
      float v0 = xb[oy], v1 = xb[oy+HWSZ], v2 = xb[oy+2*HWSZ];
      float g2 = (0.2989f*v0 + 0.587f*v1 + 0.114f*v2 + 1.f)*0.5f;
      float T = (sa*g2 + sb)*rc;
      float rT = 1.0f / T;
      float i0=(v0+1.f)*0.5f, i1=(v1+1.f)*0.5f, i2=(v2+1.f)*0.5f;
      __builtin_nontemporal_store((i0-A0)*rT + A0, &ob[oy]);
      __builtin_nontemporal_store((i1-A1)*rT + A1, &ob[oy+HWSZ]);
      __builtin_nontemporal_store((i2-A2)*rT + A2, &ob[oy+2*HWSZ]);
      int ya = y+GR+1, yr = y-GR;
      if(ya < HH){ float2 v = unpack_h2(hb[(size_t)ya*WW + xc]); sa+=v.x; sb+=v.y; }
      if(yr >= 0){ float2 v = unpack_h2(hb[(size_t)yr*WW + xc]); sa-=v.x; sb-=v.y; }
    }
  }
}

extern "C" void kernel_launch(void* const* d_in, const int* in_sizes, int n_in,
                              void* d_out, int out_size, void* d_ws, size_t ws_size,
                              hipStream_t stream) {
  const float* x = (const float*)d_in[0];
  float* out = (float*)d_out;
  char* ws = (char*)d_ws;

  const size_t NB = (size_t)NIMG*HWSZ*sizeof(float);   // 16 MiB per plane

  float* rowtmp = (float*)(ws + 0*NB);        // 16 MiB (dead before h4 written)
  float* dark   = (float*)(ws + 1*NB);        // 16 MiB (dead before h4 written)
  uint2* h4     = (uint2*)(ws + 0*NB);        // 32 MiB packed f16x4
  u32*   hab    = (u32*)(ws + 0*NB);          // 16 MiB packed f16x2 (after h4 dead)
  float* pT     = (float*)(ws + 4*NB);        // 16 MiB trans_raw
  float2* ab    = (float2*)out;               // 32 MiB of d_out (overwritten by k_final)

  char* sm = ws + 5*NB;
  u32* hist1 = (u32*)sm;                       // 512 KiB (reused as ties)
  u32* ties  = hist1;
  u32* hist2 = (u32*)(sm + 524288);            // 64 KiB
  u32* st    = (u32*)(sm + 524288 + 65536);    // 1 KiB
  float* sums= (float*)(sm + 524288 + 65536 + 1024);
  float* Abuf= (float*)(sm + 524288 + 65536 + 1024 + 512);

  // 1. dark channel (fused channel-min + separable min-pool)
  k_rowmin_f<0><<<dim3(2*NIMG*HH), dim3(256), 0, stream>>>(x, nullptr, rowtmp);
  k_colmin<0><<<dim3(HH, NIMG), dim3(128), 0, stream>>>(rowtmp, dark);
  // 2. atmospheric light (exact top-2621 with index tie-break)
  int zwords = (524288 + 65536 + 1024 + 512) / 4;
  k_zero<<<dim3((zwords+255)/256), dim3(256), 0, stream>>>((u32*)sm, zwords);
  k_hist1<<<dim3(NIMG, 8), dim3(1024), 0, stream>>>(dark, hist1);
  k_csel1<<<dim3(NIMG), dim3(1024), 0, stream>>>(hist1, st);
  k_hist2<<<dim3(NIMG, 8), dim3(1024), 0, stream>>>(dark, st, hist2);
  k_csel2<<<dim3(NIMG), dim3(1024), 0, stream>>>(hist2, st);
  k_sel4<<<dim3(NIMG, 8), dim3(1024), 0, stream>>>(dark, x, st, sums, ties);
  k_sel5<<<dim3(NIMG), dim3(1024), 0, stream>>>(x, st, sums, ties, Abuf);
  // 3. transmission raw = 1 - 0.95 * dark(img/A)
  k_rowmin_f<1><<<dim3(2*NIMG*HH), dim3(256), 0, stream>>>(x, Abuf, rowtmp);
  k_colmin<1><<<dim3(HH, NIMG), dim3(128), 0, stream>>>(rowtmp, pT);
  // 4. guided filter round 1 (guidance computed inline from x)
  k_hbox4<<<dim3(NIMG*HH), dim3(512), 0, stream>>>(x, pT, h4);
  k_vbox_ab<<<dim3(2, HH/16, NIMG), dim3(256), 0, stream>>>(h4, ab);
  // 5. guided filter round 2 -> T -> final output
  k_hbox2<<<dim3(NIMG*HH), dim3(512), 0, stream>>>(ab, hab);
  k_final<<<dim3(2, HH/16, NIMG), dim3(256), 0, stream>>>(hab, x, Abuf, out);
}